// Round 1
// 1058.218 us; speedup vs baseline: 1.2259x; 1.2259x over previous
//
#include <hip/hip_runtime.h>
#include <hip/hip_bf16.h>

#define DIM 1024
#define HID 2816
#define NEXP 7
#define TOKENS 8192

typedef __bf16 bf16x8 __attribute__((ext_vector_type(8)));
typedef float f32x4 __attribute__((ext_vector_type(4)));

static __device__ __forceinline__ unsigned short f2b(float f) {
  union { float f; unsigned int i; } c; c.f = f;
  unsigned int i = c.i;
  unsigned int r = (i + 0x7fffu + ((i >> 16) & 1u)) >> 16;
  return (unsigned short)r;
}

// async global->LDS, 16 bytes per lane. Global addr is per-lane; LDS dest = wave base + lane*16.
static __device__ __forceinline__ void gload16(const void* g, void* l) {
  __builtin_amdgcn_global_load_lds(
      (const __attribute__((address_space(1))) unsigned int*)g,
      (__attribute__((address_space(3))) unsigned int*)l, 16, 0, 0);
}

// ---------------- router: top2 of sigmoid((x@Wr)*bias), normalized -> (e0,e1,w0,w1) ----------------
__global__ __launch_bounds__(256, 2) void router_kernel(
    const float* __restrict__ X,
    const float* __restrict__ Wr,
    const float* __restrict__ bias,
    int* __restrict__ eidx,     // packed e0 | e1<<8
    float* __restrict__ ew)     // float2 (w0,w1)
{
  __shared__ float wr[DIM * NEXP];
  for (int i = threadIdx.x; i < DIM * NEXP; i += 256) wr[i] = Wr[i];
  __syncthreads();
  int t = blockIdx.x * 256 + threadIdx.x;
  float acc[NEXP];
#pragma unroll
  for (int e = 0; e < NEXP; ++e) acc[e] = 0.f;
  const float* xp = X + (size_t)t * DIM;
  for (int d0 = 0; d0 < DIM; d0 += 4) {
    float4 xv = *(const float4*)(xp + d0);
    const float* xs = (const float*)&xv;
#pragma unroll
    for (int j = 0; j < 4; ++j) {
      float xf = xs[j];
#pragma unroll
      for (int e = 0; e < NEXP; ++e) acc[e] += xf * wr[(d0 + j) * NEXP + e];
    }
  }
  float p[NEXP];
#pragma unroll
  for (int e = 0; e < NEXP; ++e)
    p[e] = 1.f / (1.f + __expf(-acc[e] * bias[e]));
  float best = -1.f; int bi = 0;
#pragma unroll
  for (int e = 0; e < NEXP; ++e) if (p[e] > best) { best = p[e]; bi = e; }
  float sec = -1.f; int si = 0;
#pragma unroll
  for (int e = 0; e < NEXP; ++e) if (e != bi && p[e] > sec) { sec = p[e]; si = e; }
  float s = best + sec;
  eidx[t] = bi | (si << 8);
  ((float2*)ew)[t] = make_float2(best / s, sec / s);
}

// ---------------- build per-expert slot lists ----------------
__global__ __launch_bounds__(256) void build_kernel(
    const int* __restrict__ eidx, const float* __restrict__ ew,
    int* __restrict__ tok, float* __restrict__ wgt, int* __restrict__ cntofs)
{
  __shared__ int cnt[NEXP], fill[NEXP], ofs[NEXP];
  if (threadIdx.x < NEXP) { cnt[threadIdx.x] = 0; fill[threadIdx.x] = 0; }
  __syncthreads();
  for (int t = threadIdx.x; t < TOKENS; t += 256) {
    int p = eidx[t];
    atomicAdd(&cnt[p & 0xff], 1);
    atomicAdd(&cnt[(p >> 8) & 0xff], 1);
  }
  __syncthreads();
  if (threadIdx.x == 0) {
    int o = 0;
    for (int e = 0; e < NEXP; ++e) { ofs[e] = o; cntofs[e] = cnt[e]; cntofs[8 + e] = o; o += cnt[e]; }
  }
  __syncthreads();
  for (int t = threadIdx.x; t < TOKENS; t += 256) {
    int p = eidx[t];
    int e0 = p & 0xff, e1 = (p >> 8) & 0xff;
    float2 w = ((const float2*)ew)[t];
    int p0 = ofs[e0] + atomicAdd(&fill[e0], 1);
    tok[p0] = t; wgt[p0] = w.x;
    int p1 = ofs[e1] + atomicAdd(&fill[e1], 1);
    tok[p1] = t; wgt[p1] = w.y;
  }
}

// ---------------- X fp32 -> bf16 ----------------
__global__ __launch_bounds__(256) void xcvt_kernel(
    const float* __restrict__ X, unsigned short* __restrict__ Xb)
{
  int i = (blockIdx.x * 256 + threadIdx.x) * 8;
  float4 v0 = *(const float4*)&X[i];
  float4 v1 = *(const float4*)&X[i + 4];
  unsigned short o[8];
  o[0] = f2b(v0.x); o[1] = f2b(v0.y); o[2] = f2b(v0.z); o[3] = f2b(v0.w);
  o[4] = f2b(v1.x); o[5] = f2b(v1.y); o[6] = f2b(v1.z); o[7] = f2b(v1.w);
  *(int4*)&Xb[i] = *(const int4*)o;
}

// ---------------- merged transpose + convert for one expert's 3 weight mats ----------------
// z=0: gate [DIM][HID] -> WguT[0];  z=1: up -> WguT[HID*DIM];  z=2: down [HID][DIM] -> WdT
__global__ __launch_bounds__(256) void transpose_cvt3_kernel(
    const float* __restrict__ g, const float* __restrict__ u, const float* __restrict__ d,
    unsigned short* __restrict__ WguT, unsigned short* __restrict__ WdT)
{
  const float* src; unsigned short* dst; int K, N;
  if (blockIdx.z == 0)      { src = g; dst = WguT;                       K = DIM; N = HID; }
  else if (blockIdx.z == 1) { src = u; dst = WguT + (size_t)HID * DIM;   K = DIM; N = HID; }
  else                      { src = d; dst = WdT;                        K = HID; N = DIM; }
  if ((int)blockIdx.x >= N / 64 || (int)blockIdx.y >= K / 64) return;

  __shared__ unsigned short t[64][72];
  const int n0 = blockIdx.x * 64, k0 = blockIdx.y * 64;
  const int tid = threadIdx.x;
  const int kl = tid >> 4, nl = (tid & 15) * 4;
#pragma unroll
  for (int i = 0; i < 4; ++i) {
    int k = kl + i * 16;
    float4 v = *(const float4*)&src[(size_t)(k0 + k) * N + n0 + nl];
    t[nl + 0][k] = f2b(v.x); t[nl + 1][k] = f2b(v.y);
    t[nl + 2][k] = f2b(v.z); t[nl + 3][k] = f2b(v.w);
  }
  __syncthreads();
  const int nl2 = tid >> 3, kc = (tid & 7) * 8;
#pragma unroll
  for (int i = 0; i < 2; ++i) {
    int n = nl2 + i * 32;
    *(int4*)&dst[(size_t)(n0 + n) * K + k0 + kc] = *(const int4*)&t[n][kc];
  }
}

// ======== BK=64 GEMM kernels with XOR-swizzled LDS (conflict-free ds_read_b128) ========
// LDS tile rows are 128 B (64 bf16) = 8 granules of 16 B. LDS (row, g) holds global
// (row, g ^ (row&7)). Staging pre-swizzles the GLOBAL source (gload_lds dest stays linear);
// readers XOR the granule with (row&7) = (c&7), a per-lane constant.

// ---------------- dense fused gate+up (shared expert) ----------------
__global__ __launch_bounds__(256, 2) void gateup_kernel(
    const unsigned short* __restrict__ Xb,
    const unsigned short* __restrict__ Wgu,
    unsigned short* __restrict__ H)
{
  __shared__ __align__(16) unsigned short As[128 * 64];
  __shared__ __align__(16) unsigned short Bgs[64 * 64];
  __shared__ __align__(16) unsigned short Bus[64 * 64];
  const int m0 = blockIdx.y * 128;
  const int n0 = blockIdx.x * 64;
  const int tid = threadIdx.x;
  const int lane = tid & 63;
  const int w = tid >> 6;
  const int wm = (w & 1) * 64;
  const int wn = (w >> 1) * 32;
  const int c = lane & 15;
  const int q = lane >> 4;
  const int cx = c & 7;

  const unsigned short* Wg = Wgu;
  const unsigned short* Wu = Wgu + (size_t)HID * DIM;

  const int r8 = lane >> 3;                  // staged row & 7
  const int swz = ((lane & 7) ^ r8) * 8;     // pre-swizzled granule (ushort units)
  const int wrow = w * 8 + r8;               // 0..31

  const unsigned short* aptr[4];
#pragma unroll
  for (int i = 0; i < 4; ++i)
    aptr[i] = Xb + (size_t)(m0 + i * 32 + wrow) * DIM + swz;
  const unsigned short* gptr[2];
  const unsigned short* uptr[2];
#pragma unroll
  for (int i = 0; i < 2; ++i) {
    gptr[i] = Wg + (size_t)(n0 + i * 32 + wrow) * DIM + swz;
    uptr[i] = Wu + (size_t)(n0 + i * 32 + wrow) * DIM + swz;
  }

  f32x4 accg[4][2], accu[4][2];
#pragma unroll
  for (int mi = 0; mi < 4; ++mi)
#pragma unroll
    for (int ni = 0; ni < 2; ++ni) {
      accg[mi][ni] = {0.f, 0.f, 0.f, 0.f};
      accu[mi][ni] = {0.f, 0.f, 0.f, 0.f};
    }

  for (int k0 = 0; k0 < DIM; k0 += 64) {
    __syncthreads();
#pragma unroll
    for (int i = 0; i < 4; ++i) gload16(aptr[i] + k0, &As[i * 2048 + tid * 8]);
#pragma unroll
    for (int i = 0; i < 2; ++i) {
      gload16(gptr[i] + k0, &Bgs[i * 2048 + tid * 8]);
      gload16(uptr[i] + k0, &Bus[i * 2048 + tid * 8]);
    }
    __syncthreads();
#pragma unroll
    for (int h = 0; h < 2; ++h) {
      const int go = ((h * 4 + q) ^ cx) * 8;
      bf16x8 a[4], bg[2], bu[2];
#pragma unroll
      for (int mi = 0; mi < 4; ++mi)
        a[mi] = *(const bf16x8*)&As[(wm + mi * 16 + c) * 64 + go];
#pragma unroll
      for (int ni = 0; ni < 2; ++ni) {
        bg[ni] = *(const bf16x8*)&Bgs[(wn + ni * 16 + c) * 64 + go];
        bu[ni] = *(const bf16x8*)&Bus[(wn + ni * 16 + c) * 64 + go];
      }
#pragma unroll
      for (int mi = 0; mi < 4; ++mi)
#pragma unroll
        for (int ni = 0; ni < 2; ++ni) {
          accg[mi][ni] = __builtin_amdgcn_mfma_f32_16x16x32_bf16(a[mi], bg[ni], accg[mi][ni], 0, 0, 0);
          accu[mi][ni] = __builtin_amdgcn_mfma_f32_16x16x32_bf16(a[mi], bu[ni], accu[mi][ni], 0, 0, 0);
        }
    }
  }
#pragma unroll
  for (int mi = 0; mi < 4; ++mi)
#pragma unroll
    for (int ni = 0; ni < 2; ++ni)
#pragma unroll
      for (int r = 0; r < 4; ++r) {
        int row = wm + mi * 16 + q * 4 + r;
        int col = wn + ni * 16 + c;
        float g = accg[mi][ni][r];
        float u = accu[mi][ni][r];
        float h = (g / (1.f + __expf(-g))) * u;
        H[(size_t)(m0 + row) * HID + n0 + col] = f2b(h);
      }
}

// ---------------- sparse fused gate+up: gathered tokens, weight folded into H ----------------
__global__ __launch_bounds__(256, 2) void gateup_sparse_kernel(
    const unsigned short* __restrict__ Xb,
    const unsigned short* __restrict__ Wgu,
    const int* __restrict__ tok, const float* __restrict__ wgt,
    const int* __restrict__ cntofs, int e,
    unsigned short* __restrict__ H)
{
  const int cnt = cntofs[e];
  const int mb = blockIdx.y;
  if (mb * 128 >= cnt) return;
  const int ofs = cntofs[8 + e];

  __shared__ __align__(16) unsigned short As[128 * 64];
  __shared__ __align__(16) unsigned short Bgs[64 * 64];
  __shared__ __align__(16) unsigned short Bus[64 * 64];
  __shared__ float wl[128];

  const int n0 = blockIdx.x * 64;
  const int tid = threadIdx.x;
  const int lane = tid & 63;
  const int w = tid >> 6;
  const int wm = (w & 1) * 64;
  const int wn = (w >> 1) * 32;
  const int c = lane & 15;
  const int q = lane >> 4;
  const int cx = c & 7;

  if (tid < 128)
    wl[tid] = (mb * 128 + tid < cnt) ? wgt[ofs + mb * 128 + tid] : 0.f;

  const unsigned short* Wg = Wgu;
  const unsigned short* Wu = Wgu + (size_t)HID * DIM;

  const int r8 = lane >> 3;
  const int swz = ((lane & 7) ^ r8) * 8;
  const int wrow = w * 8 + r8;

  const unsigned short* aptr[4];
#pragma unroll
  for (int i = 0; i < 4; ++i) {
    int s = mb * 128 + i * 32 + wrow;
    int t = (s < cnt) ? tok[ofs + s] : 0;
    aptr[i] = Xb + (size_t)t * DIM + swz;
  }
  const unsigned short* gptr[2];
  const unsigned short* uptr[2];
#pragma unroll
  for (int i = 0; i < 2; ++i) {
    gptr[i] = Wg + (size_t)(n0 + i * 32 + wrow) * DIM + swz;
    uptr[i] = Wu + (size_t)(n0 + i * 32 + wrow) * DIM + swz;
  }

  f32x4 accg[4][2], accu[4][2];
#pragma unroll
  for (int mi = 0; mi < 4; ++mi)
#pragma unroll
    for (int ni = 0; ni < 2; ++ni) {
      accg[mi][ni] = {0.f, 0.f, 0.f, 0.f};
      accu[mi][ni] = {0.f, 0.f, 0.f, 0.f};
    }

  for (int k0 = 0; k0 < DIM; k0 += 64) {
    __syncthreads();
#pragma unroll
    for (int i = 0; i < 4; ++i) gload16(aptr[i] + k0, &As[i * 2048 + tid * 8]);
#pragma unroll
    for (int i = 0; i < 2; ++i) {
      gload16(gptr[i] + k0, &Bgs[i * 2048 + tid * 8]);
      gload16(uptr[i] + k0, &Bus[i * 2048 + tid * 8]);
    }
    __syncthreads();
#pragma unroll
    for (int h = 0; h < 2; ++h) {
      const int go = ((h * 4 + q) ^ cx) * 8;
      bf16x8 a[4], bg[2], bu[2];
#pragma unroll
      for (int mi = 0; mi < 4; ++mi)
        a[mi] = *(const bf16x8*)&As[(wm + mi * 16 + c) * 64 + go];
#pragma unroll
      for (int ni = 0; ni < 2; ++ni) {
        bg[ni] = *(const bf16x8*)&Bgs[(wn + ni * 16 + c) * 64 + go];
        bu[ni] = *(const bf16x8*)&Bus[(wn + ni * 16 + c) * 64 + go];
      }
#pragma unroll
      for (int mi = 0; mi < 4; ++mi)
#pragma unroll
        for (int ni = 0; ni < 2; ++ni) {
          accg[mi][ni] = __builtin_amdgcn_mfma_f32_16x16x32_bf16(a[mi], bg[ni], accg[mi][ni], 0, 0, 0);
          accu[mi][ni] = __builtin_amdgcn_mfma_f32_16x16x32_bf16(a[mi], bu[ni], accu[mi][ni], 0, 0, 0);
        }
    }
  }
#pragma unroll
  for (int mi = 0; mi < 4; ++mi)
#pragma unroll
    for (int ni = 0; ni < 2; ++ni)
#pragma unroll
      for (int r = 0; r < 4; ++r) {
        int row = wm + mi * 16 + q * 4 + r;
        int col = wn + ni * 16 + c;
        float g = accg[mi][ni][r];
        float u = accu[mi][ni][r];
        float h = (g / (1.f + __expf(-g))) * u * wl[row];
        H[(size_t)(mb * 128 + row) * HID + n0 + col] = f2b(h);
      }
}

// ---------------- dense down (shared expert, initializes out) ----------------
__global__ __launch_bounds__(256, 2) void down_dense_kernel(
    const unsigned short* __restrict__ Hm,
    const unsigned short* __restrict__ WdT,
    float* __restrict__ out)
{
  __shared__ __align__(16) unsigned short As[128 * 64];
  __shared__ __align__(16) unsigned short Bs[128 * 64];
  const int m0 = blockIdx.y * 128;
  const int n0 = blockIdx.x * 128;
  const int tid = threadIdx.x;
  const int lane = tid & 63;
  const int w4 = tid >> 6;
  const int wm = (w4 & 1) * 64;
  const int wn = (w4 >> 1) * 64;
  const int c = lane & 15;
  const int q = lane >> 4;
  const int cx = c & 7;

  const int r8 = lane >> 3;
  const int swz = ((lane & 7) ^ r8) * 8;
  const int wrow = w4 * 8 + r8;

  const unsigned short* aptr[4];
  const unsigned short* bptr[4];
#pragma unroll
  for (int i = 0; i < 4; ++i) {
    aptr[i] = Hm + (size_t)(m0 + i * 32 + wrow) * HID + swz;
    bptr[i] = WdT + (size_t)(n0 + i * 32 + wrow) * HID + swz;
  }

  f32x4 acc[4][4];
#pragma unroll
  for (int mi = 0; mi < 4; ++mi)
#pragma unroll
    for (int ni = 0; ni < 4; ++ni) acc[mi][ni] = {0.f, 0.f, 0.f, 0.f};

  for (int k0 = 0; k0 < HID; k0 += 64) {
    __syncthreads();
#pragma unroll
    for (int i = 0; i < 4; ++i) {
      gload16(aptr[i] + k0, &As[i * 2048 + tid * 8]);
      gload16(bptr[i] + k0, &Bs[i * 2048 + tid * 8]);
    }
    __syncthreads();
#pragma unroll
    for (int h = 0; h < 2; ++h) {
      const int go = ((h * 4 + q) ^ cx) * 8;
      bf16x8 a[4], b[4];
#pragma unroll
      for (int mi = 0; mi < 4; ++mi)
        a[mi] = *(const bf16x8*)&As[(wm + mi * 16 + c) * 64 + go];
#pragma unroll
      for (int ni = 0; ni < 4; ++ni)
        b[ni] = *(const bf16x8*)&Bs[(wn + ni * 16 + c) * 64 + go];
#pragma unroll
      for (int mi = 0; mi < 4; ++mi)
#pragma unroll
        for (int ni = 0; ni < 4; ++ni)
          acc[mi][ni] = __builtin_amdgcn_mfma_f32_16x16x32_bf16(a[mi], b[ni], acc[mi][ni], 0, 0, 0);
    }
  }
#pragma unroll
  for (int mi = 0; mi < 4; ++mi)
#pragma unroll
    for (int r = 0; r < 4; ++r) {
      int trow = m0 + wm + mi * 16 + q * 4 + r;
#pragma unroll
      for (int ni = 0; ni < 4; ++ni) {
        int col = n0 + wn + ni * 16 + c;
        out[(size_t)trow * DIM + col] = acc[mi][ni][r];
      }
    }
}

// ---------------- sparse down: compacted H, split-K=2, atomic scatter-accumulate ----------------
__global__ __launch_bounds__(256, 2) void down_sparse_kernel(
    const unsigned short* __restrict__ Hm,
    const unsigned short* __restrict__ WdT,
    const int* __restrict__ tok, const int* __restrict__ cntofs, int e,
    float* __restrict__ out)
{
  const int cnt = cntofs[e];
  const int mb = blockIdx.y;
  if (mb * 128 >= cnt) return;
  const int ofs = cntofs[8 + e];
  const int kbase = blockIdx.z * (HID / 2);   // split-K half

  __shared__ __align__(16) unsigned short As[128 * 64];
  __shared__ __align__(16) unsigned short Bs[128 * 64];
  __shared__ int tl[128];
  const int n0 = blockIdx.x * 128;
  const int tid = threadIdx.x;
  const int lane = tid & 63;
  const int w4 = tid >> 6;
  const int wm = (w4 & 1) * 64;
  const int wn = (w4 >> 1) * 64;
  const int c = lane & 15;
  const int q = lane >> 4;
  const int cx = c & 7;

  if (tid < 128)
    tl[tid] = (mb * 128 + tid < cnt) ? tok[ofs + mb * 128 + tid] : 0;

  const int r8 = lane >> 3;
  const int swz = ((lane & 7) ^ r8) * 8;
  const int wrow = w4 * 8 + r8;

  const unsigned short* aptr[4];
  const unsigned short* bptr[4];
#pragma unroll
  for (int i = 0; i < 4; ++i) {
    aptr[i] = Hm + (size_t)(mb * 128 + i * 32 + wrow) * HID + kbase + swz;
    bptr[i] = WdT + (size_t)(n0 + i * 32 + wrow) * HID + kbase + swz;
  }

  f32x4 acc[4][4];
#pragma unroll
  for (int mi = 0; mi < 4; ++mi)
#pragma unroll
    for (int ni = 0; ni < 4; ++ni) acc[mi][ni] = {0.f, 0.f, 0.f, 0.f};

  for (int k0 = 0; k0 < HID / 2; k0 += 64) {
    __syncthreads();
#pragma unroll
    for (int i = 0; i < 4; ++i) {
      gload16(aptr[i] + k0, &As[i * 2048 + tid * 8]);
      gload16(bptr[i] + k0, &Bs[i * 2048 + tid * 8]);
    }
    __syncthreads();
#pragma unroll
    for (int h = 0; h < 2; ++h) {
      const int go = ((h * 4 + q) ^ cx) * 8;
      bf16x8 a[4], b[4];
#pragma unroll
      for (int mi = 0; mi < 4; ++mi)
        a[mi] = *(const bf16x8*)&As[(wm + mi * 16 + c) * 64 + go];
#pragma unroll
      for (int ni = 0; ni < 4; ++ni)
        b[ni] = *(const bf16x8*)&Bs[(wn + ni * 16 + c) * 64 + go];
#pragma unroll
      for (int mi = 0; mi < 4; ++mi)
#pragma unroll
        for (int ni = 0; ni < 4; ++ni)
          acc[mi][ni] = __builtin_amdgcn_mfma_f32_16x16x32_bf16(a[mi], b[ni], acc[mi][ni], 0, 0, 0);
    }
  }
#pragma unroll
  for (int mi = 0; mi < 4; ++mi)
#pragma unroll
    for (int r = 0; r < 4; ++r) {
      int lr = wm + mi * 16 + q * 4 + r;
      if (mb * 128 + lr < cnt) {
        int t = tl[lr];
#pragma unroll
        for (int ni = 0; ni < 4; ++ni) {
          int col = n0 + wn + ni * 16 + c;
          atomicAdd(&out[(size_t)t * DIM + col], acc[mi][ni][r]);
        }
      }
    }
}

extern "C" void kernel_launch(void* const* d_in, const int* in_sizes, int n_in,
                              void* d_out, int out_size, void* d_ws, size_t ws_size,
                              hipStream_t stream) {
  (void)in_sizes; (void)n_in; (void)out_size; (void)ws_size;
  const float* x   = (const float*)d_in[0];
  const float* sg  = (const float*)d_in[1];
  const float* su  = (const float*)d_in[2];
  const float* sd  = (const float*)d_in[3];
  const float* rg  = (const float*)d_in[4];
  const float* ru  = (const float*)d_in[5];
  const float* rd  = (const float*)d_in[6];
  const float* wrr = (const float*)d_in[7];
  const float* rb  = (const float*)d_in[8];
  float* out = (float*)d_out;

  char* ws = (char*)d_ws;
  unsigned short* Xb  = (unsigned short*)ws;               // 16,777,216
  unsigned short* H   = (unsigned short*)(ws + 16777216);  // 46,137,344
  unsigned short* Wgu = (unsigned short*)(ws + 62914560);  // 11,534,336
  unsigned short* Wd  = (unsigned short*)(ws + 74448896);  //  5,767,168
  int*   tok          = (int*)(ws + 80216064);             //     65,536
  float* wgt          = (float*)(ws + 80281600);           //     65,536
  int*   cntofs       = (int*)(ws + 80347136);             //         64
  // eidx/ew parked inside H (consumed by build before any gateup writes H)
  int*   eidx = (int*)H;
  float* ew   = (float*)((char*)H + 32768);

  dim3 blk(256);
  router_kernel<<<dim3(TOKENS / 256), blk, 0, stream>>>(x, wrr, rb, eidx, ew);
  xcvt_kernel<<<dim3(TOKENS * DIM / (8 * 256)), blk, 0, stream>>>(x, Xb);
  build_kernel<<<dim3(1), blk, 0, stream>>>(eidx, ew, tok, wgt, cntofs);

  dim3 ggu(HID / 64, TOKENS / 128);
  dim3 gdn(DIM / 128, TOKENS / 128);
  dim3 gdns(DIM / 128, TOKENS / 128, 2);
  dim3 tall(HID / 64, HID / 64, 3);   // covers max dims; kernel early-outs extras

  for (int e = 0; e < 8; ++e) {
    const float* eg = (e == 0) ? sg : rg + (size_t)(e - 1) * DIM * HID;
    const float* eu = (e == 0) ? su : ru + (size_t)(e - 1) * DIM * HID;
    const float* ed = (e == 0) ? sd : rd + (size_t)(e - 1) * HID * DIM;
    transpose_cvt3_kernel<<<tall, blk, 0, stream>>>(eg, eu, ed, Wgu, Wd);
    if (e == 0) {
      gateup_kernel<<<ggu, blk, 0, stream>>>(Xb, Wgu, H);
      down_dense_kernel<<<gdn, blk, 0, stream>>>(H, Wd, out);
    } else {
      gateup_sparse_kernel<<<ggu, blk, 0, stream>>>(Xb, Wgu, tok, wgt, cntofs, e - 1, H);
      down_sparse_kernel<<<gdns, blk, 0, stream>>>(H, Wd, tok, cntofs, e - 1, out);
    }
  }
}

// Round 2
// 946.730 us; speedup vs baseline: 1.3703x; 1.1178x over previous
//
#include <hip/hip_runtime.h>
#include <hip/hip_bf16.h>

#define DIM 1024
#define HID 2816
#define NEXP 7
#define TOKENS 8192

// ---- merged-workspace layout (bytes) ----
#define MW_XB    0ull
#define MW_H     16777216ull           // 17280 rows x HID bf16 = 97,320,960
#define MW_WGU   114098176ull          // 8 x 2*HID*DIM bf16   = 92,274,688
#define MW_WD    206372864ull          // 8 x HID*DIM bf16     = 46,137,344
#define MW_TOK   252510208ull          // 17280 x int
#define MW_WGT   252579328ull          // 17280 x float
#define MW_META  252648448ull          // 512 ints
#define MW_NEED  252650496ull

typedef __bf16 bf16x8 __attribute__((ext_vector_type(8)));
typedef float f32x4 __attribute__((ext_vector_type(4)));

static __device__ __forceinline__ unsigned short f2b(float f) {
  union { float f; unsigned int i; } c; c.f = f;
  unsigned int i = c.i;
  unsigned int r = (i + 0x7fffu + ((i >> 16) & 1u)) >> 16;
  return (unsigned short)r;
}

// async global->LDS, 16 bytes per lane. Global addr is per-lane; LDS dest = wave base + lane*16.
static __device__ __forceinline__ void gload16(const void* g, void* l) {
  __builtin_amdgcn_global_load_lds(
      (const __attribute__((address_space(1))) unsigned int*)g,
      (__attribute__((address_space(3))) unsigned int*)l, 16, 0, 0);
}

// ---------------- router: top2 of sigmoid((x@Wr)*bias), normalized -> (e0,e1,w0,w1) ----------------
__global__ __launch_bounds__(256, 2) void router_kernel(
    const float* __restrict__ X,
    const float* __restrict__ Wr,
    const float* __restrict__ bias,
    int* __restrict__ eidx,     // packed e0 | e1<<8
    float* __restrict__ ew)     // float2 (w0,w1)
{
  __shared__ float wr[DIM * NEXP];
  for (int i = threadIdx.x; i < DIM * NEXP; i += 256) wr[i] = Wr[i];
  __syncthreads();
  int t = blockIdx.x * 256 + threadIdx.x;
  float acc[NEXP];
#pragma unroll
  for (int e = 0; e < NEXP; ++e) acc[e] = 0.f;
  const float* xp = X + (size_t)t * DIM;
  for (int d0 = 0; d0 < DIM; d0 += 4) {
    float4 xv = *(const float4*)(xp + d0);
    const float* xs = (const float*)&xv;
#pragma unroll
    for (int j = 0; j < 4; ++j) {
      float xf = xs[j];
#pragma unroll
      for (int e = 0; e < NEXP; ++e) acc[e] += xf * wr[(d0 + j) * NEXP + e];
    }
  }
  float p[NEXP];
#pragma unroll
  for (int e = 0; e < NEXP; ++e)
    p[e] = 1.f / (1.f + __expf(-acc[e] * bias[e]));
  float best = -1.f; int bi = 0;
#pragma unroll
  for (int e = 0; e < NEXP; ++e) if (p[e] > best) { best = p[e]; bi = e; }
  float sec = -1.f; int si = 0;
#pragma unroll
  for (int e = 0; e < NEXP; ++e) if (e != bi && p[e] > sec) { sec = p[e]; si = e; }
  float s = best + sec;
  eidx[t] = bi | (si << 8);
  ((float2*)ew)[t] = make_float2(best / s, sec / s);
}

// ---------------- build per-expert slot lists (+ block map in padded mode) ----------------
// meta[e]    = cnt[e]            (e<7)
// meta[8+e]  = slot base ofs[e]  (padded to 128 in padmode)
// meta[15]   = nblk  (padmode only)
// meta[16+i] = blkmap: e | (mb<<3)   (padmode only)
__global__ __launch_bounds__(256) void build_kernel(
    const int* __restrict__ eidx, const float* __restrict__ ew,
    int* __restrict__ tok, float* __restrict__ wgt, int* __restrict__ meta,
    int padmode)
{
  __shared__ int cnt[NEXP], fill[NEXP], ofs[NEXP];
  if (threadIdx.x < NEXP) { cnt[threadIdx.x] = 0; fill[threadIdx.x] = 0; }
  __syncthreads();
  for (int t = threadIdx.x; t < TOKENS; t += 256) {
    int p = eidx[t];
    atomicAdd(&cnt[p & 0xff], 1);
    atomicAdd(&cnt[(p >> 8) & 0xff], 1);
  }
  __syncthreads();
  if (threadIdx.x == 0) {
    int o = 0, nb = 0;
    for (int e = 0; e < NEXP; ++e) {
      ofs[e] = o;
      meta[e] = cnt[e];
      meta[8 + e] = o;
      if (padmode) {
        int b = (cnt[e] + 127) >> 7;
        for (int i = 0; i < b; ++i) meta[16 + nb++] = e | (i << 3);
        o += b << 7;
      } else {
        o += cnt[e];
      }
    }
    meta[15] = nb;
  }
  __syncthreads();
  for (int t = threadIdx.x; t < TOKENS; t += 256) {
    int p = eidx[t];
    int e0 = p & 0xff, e1 = (p >> 8) & 0xff;
    float2 w = ((const float2*)ew)[t];
    int p0 = ofs[e0] + atomicAdd(&fill[e0], 1);
    tok[p0] = t; wgt[p0] = w.x;
    int p1 = ofs[e1] + atomicAdd(&fill[e1], 1);
    tok[p1] = t; wgt[p1] = w.y;
  }
}

// ---------------- X fp32 -> bf16 ----------------
__global__ __launch_bounds__(256) void xcvt_kernel(
    const float* __restrict__ X, unsigned short* __restrict__ Xb)
{
  int i = (blockIdx.x * 256 + threadIdx.x) * 8;
  float4 v0 = *(const float4*)&X[i];
  float4 v1 = *(const float4*)&X[i + 4];
  unsigned short o[8];
  o[0] = f2b(v0.x); o[1] = f2b(v0.y); o[2] = f2b(v0.z); o[3] = f2b(v0.w);
  o[4] = f2b(v1.x); o[5] = f2b(v1.y); o[6] = f2b(v1.z); o[7] = f2b(v1.w);
  *(int4*)&Xb[i] = *(const int4*)o;
}

// ---------------- transpose + convert, all experts, exact flat grid ----------------
// 2112 blocks per expert: m=0 gate (704 = 44n x 16k), m=1 up, m=2 down (704 = 16n x 44k)
// e=0 -> shared weights, e>=1 -> routed expert e-1.
__global__ __launch_bounds__(256) void transpose_all_kernel(
    const float* __restrict__ sg, const float* __restrict__ su, const float* __restrict__ sd,
    const float* __restrict__ rg, const float* __restrict__ ru, const float* __restrict__ rd,
    unsigned short* __restrict__ WguA, unsigned short* __restrict__ WdA)
{
  int b = blockIdx.x;
  int e = b / 2112, r = b % 2112;
  int m = r / 704, q2 = r % 704;
  const float* src; unsigned short* dst; int K, N, nb, kb;
  if (m == 0) {
    src = e ? rg + (size_t)(e - 1) * DIM * HID : sg;
    dst = WguA + (size_t)e * (2 * (size_t)HID * DIM);
    K = DIM; N = HID; nb = q2 % 44; kb = q2 / 44;
  } else if (m == 1) {
    src = e ? ru + (size_t)(e - 1) * DIM * HID : su;
    dst = WguA + (size_t)e * (2 * (size_t)HID * DIM) + (size_t)HID * DIM;
    K = DIM; N = HID; nb = q2 % 44; kb = q2 / 44;
  } else {
    src = e ? rd + (size_t)(e - 1) * HID * DIM : sd;
    dst = WdA + (size_t)e * ((size_t)HID * DIM);
    K = HID; N = DIM; nb = q2 % 16; kb = q2 / 16;
  }
  __shared__ unsigned short t[64][72];
  const int n0 = nb * 64, k0 = kb * 64;
  const int tid = threadIdx.x;
  const int kl = tid >> 4, nl = (tid & 15) * 4;
#pragma unroll
  for (int i = 0; i < 4; ++i) {
    int k = kl + i * 16;
    float4 v = *(const float4*)&src[(size_t)(k0 + k) * N + n0 + nl];
    t[nl + 0][k] = f2b(v.x); t[nl + 1][k] = f2b(v.y);
    t[nl + 2][k] = f2b(v.z); t[nl + 3][k] = f2b(v.w);
  }
  __syncthreads();
  const int nl2 = tid >> 3, kc = (tid & 7) * 8;
#pragma unroll
  for (int i = 0; i < 2; ++i) {
    int n = nl2 + i * 32;
    *(int4*)&dst[(size_t)(n0 + n) * K + k0 + kc] = *(const int4*)&t[n][kc];
  }
}

// ======== BK=64 GEMM kernels with XOR-swizzled LDS (conflict-free ds_read_b128) ========
// LDS tile rows are 128 B (64 bf16) = 8 granules of 16 B. LDS (row, g) holds global
// (row, g ^ (row&7)). Staging pre-swizzles the GLOBAL source (gload_lds dest stays linear);
// readers XOR the granule with (row&7) = (c&7), a per-lane constant.

// ---------------- dense fused gate+up (shared expert) ----------------
__global__ __launch_bounds__(256, 2) void gateup_kernel(
    const unsigned short* __restrict__ Xb,
    const unsigned short* __restrict__ Wgu,
    unsigned short* __restrict__ H)
{
  __shared__ __align__(16) unsigned short As[128 * 64];
  __shared__ __align__(16) unsigned short Bgs[64 * 64];
  __shared__ __align__(16) unsigned short Bus[64 * 64];
  const int m0 = blockIdx.y * 128;
  const int n0 = blockIdx.x * 64;
  const int tid = threadIdx.x;
  const int lane = tid & 63;
  const int w = tid >> 6;
  const int wm = (w & 1) * 64;
  const int wn = (w >> 1) * 32;
  const int c = lane & 15;
  const int q = lane >> 4;
  const int cx = c & 7;

  const unsigned short* Wg = Wgu;
  const unsigned short* Wu = Wgu + (size_t)HID * DIM;

  const int r8 = lane >> 3;
  const int swz = ((lane & 7) ^ r8) * 8;
  const int wrow = w * 8 + r8;

  const unsigned short* aptr[4];
#pragma unroll
  for (int i = 0; i < 4; ++i)
    aptr[i] = Xb + (size_t)(m0 + i * 32 + wrow) * DIM + swz;
  const unsigned short* gptr[2];
  const unsigned short* uptr[2];
#pragma unroll
  for (int i = 0; i < 2; ++i) {
    gptr[i] = Wg + (size_t)(n0 + i * 32 + wrow) * DIM + swz;
    uptr[i] = Wu + (size_t)(n0 + i * 32 + wrow) * DIM + swz;
  }

  f32x4 accg[4][2], accu[4][2];
#pragma unroll
  for (int mi = 0; mi < 4; ++mi)
#pragma unroll
    for (int ni = 0; ni < 2; ++ni) {
      accg[mi][ni] = {0.f, 0.f, 0.f, 0.f};
      accu[mi][ni] = {0.f, 0.f, 0.f, 0.f};
    }

  for (int k0 = 0; k0 < DIM; k0 += 64) {
    __syncthreads();
#pragma unroll
    for (int i = 0; i < 4; ++i) gload16(aptr[i] + k0, &As[i * 2048 + tid * 8]);
#pragma unroll
    for (int i = 0; i < 2; ++i) {
      gload16(gptr[i] + k0, &Bgs[i * 2048 + tid * 8]);
      gload16(uptr[i] + k0, &Bus[i * 2048 + tid * 8]);
    }
    __syncthreads();
#pragma unroll
    for (int h = 0; h < 2; ++h) {
      const int go = ((h * 4 + q) ^ cx) * 8;
      bf16x8 a[4], bg[2], bu[2];
#pragma unroll
      for (int mi = 0; mi < 4; ++mi)
        a[mi] = *(const bf16x8*)&As[(wm + mi * 16 + c) * 64 + go];
#pragma unroll
      for (int ni = 0; ni < 2; ++ni) {
        bg[ni] = *(const bf16x8*)&Bgs[(wn + ni * 16 + c) * 64 + go];
        bu[ni] = *(const bf16x8*)&Bus[(wn + ni * 16 + c) * 64 + go];
      }
#pragma unroll
      for (int mi = 0; mi < 4; ++mi)
#pragma unroll
        for (int ni = 0; ni < 2; ++ni) {
          accg[mi][ni] = __builtin_amdgcn_mfma_f32_16x16x32_bf16(a[mi], bg[ni], accg[mi][ni], 0, 0, 0);
          accu[mi][ni] = __builtin_amdgcn_mfma_f32_16x16x32_bf16(a[mi], bu[ni], accu[mi][ni], 0, 0, 0);
        }
    }
  }
#pragma unroll
  for (int mi = 0; mi < 4; ++mi)
#pragma unroll
    for (int ni = 0; ni < 2; ++ni)
#pragma unroll
      for (int r = 0; r < 4; ++r) {
        int row = wm + mi * 16 + q * 4 + r;
        int col = wn + ni * 16 + c;
        float g = accg[mi][ni][r];
        float u = accu[mi][ni][r];
        float h = (g / (1.f + __expf(-g))) * u;
        H[(size_t)(m0 + row) * HID + n0 + col] = f2b(h);
      }
}

// ---------------- merged sparse fused gate+up: all experts, one launch ----------------
__global__ __launch_bounds__(256, 2) void gateup_sparse_all_kernel(
    const unsigned short* __restrict__ Xb,
    const unsigned short* __restrict__ WguR,   // routed expert 0 base (slot 1 of WguA)
    const int* __restrict__ tok, const float* __restrict__ wgt,
    const int* __restrict__ meta,
    unsigned short* __restrict__ H)
{
  const int yb = blockIdx.y;
  if (yb >= meta[15]) return;
  const int bm = meta[16 + yb];
  const int e = bm & 7, mb = bm >> 3;
  const int cnt = meta[e];
  const int pofs = meta[8 + e];
  const unsigned short* Wgu = WguR + (size_t)e * (2 * (size_t)HID * DIM);

  __shared__ __align__(16) unsigned short As[128 * 64];
  __shared__ __align__(16) unsigned short Bgs[64 * 64];
  __shared__ __align__(16) unsigned short Bus[64 * 64];
  __shared__ float wl[128];

  const int n0 = blockIdx.x * 64;
  const int tid = threadIdx.x;
  const int lane = tid & 63;
  const int w = tid >> 6;
  const int wm = (w & 1) * 64;
  const int wn = (w >> 1) * 32;
  const int c = lane & 15;
  const int q = lane >> 4;
  const int cx = c & 7;

  if (tid < 128)
    wl[tid] = (mb * 128 + tid < cnt) ? wgt[pofs + mb * 128 + tid] : 0.f;

  const unsigned short* Wg = Wgu;
  const unsigned short* Wu = Wgu + (size_t)HID * DIM;

  const int r8 = lane >> 3;
  const int swz = ((lane & 7) ^ r8) * 8;
  const int wrow = w * 8 + r8;

  const unsigned short* aptr[4];
#pragma unroll
  for (int i = 0; i < 4; ++i) {
    int s = mb * 128 + i * 32 + wrow;
    int t = (s < cnt) ? tok[pofs + s] : 0;
    aptr[i] = Xb + (size_t)t * DIM + swz;
  }
  const unsigned short* gptr[2];
  const unsigned short* uptr[2];
#pragma unroll
  for (int i = 0; i < 2; ++i) {
    gptr[i] = Wg + (size_t)(n0 + i * 32 + wrow) * DIM + swz;
    uptr[i] = Wu + (size_t)(n0 + i * 32 + wrow) * DIM + swz;
  }

  f32x4 accg[4][2], accu[4][2];
#pragma unroll
  for (int mi = 0; mi < 4; ++mi)
#pragma unroll
    for (int ni = 0; ni < 2; ++ni) {
      accg[mi][ni] = {0.f, 0.f, 0.f, 0.f};
      accu[mi][ni] = {0.f, 0.f, 0.f, 0.f};
    }

  for (int k0 = 0; k0 < DIM; k0 += 64) {
    __syncthreads();
#pragma unroll
    for (int i = 0; i < 4; ++i) gload16(aptr[i] + k0, &As[i * 2048 + tid * 8]);
#pragma unroll
    for (int i = 0; i < 2; ++i) {
      gload16(gptr[i] + k0, &Bgs[i * 2048 + tid * 8]);
      gload16(uptr[i] + k0, &Bus[i * 2048 + tid * 8]);
    }
    __syncthreads();
#pragma unroll
    for (int h = 0; h < 2; ++h) {
      const int go = ((h * 4 + q) ^ cx) * 8;
      bf16x8 a[4], bg[2], bu[2];
#pragma unroll
      for (int mi = 0; mi < 4; ++mi)
        a[mi] = *(const bf16x8*)&As[(wm + mi * 16 + c) * 64 + go];
#pragma unroll
      for (int ni = 0; ni < 2; ++ni) {
        bg[ni] = *(const bf16x8*)&Bgs[(wn + ni * 16 + c) * 64 + go];
        bu[ni] = *(const bf16x8*)&Bus[(wn + ni * 16 + c) * 64 + go];
      }
#pragma unroll
      for (int mi = 0; mi < 4; ++mi)
#pragma unroll
        for (int ni = 0; ni < 2; ++ni) {
          accg[mi][ni] = __builtin_amdgcn_mfma_f32_16x16x32_bf16(a[mi], bg[ni], accg[mi][ni], 0, 0, 0);
          accu[mi][ni] = __builtin_amdgcn_mfma_f32_16x16x32_bf16(a[mi], bu[ni], accu[mi][ni], 0, 0, 0);
        }
    }
  }
#pragma unroll
  for (int mi = 0; mi < 4; ++mi)
#pragma unroll
    for (int ni = 0; ni < 2; ++ni)
#pragma unroll
      for (int r = 0; r < 4; ++r) {
        int row = wm + mi * 16 + q * 4 + r;
        int col = wn + ni * 16 + c;
        float g = accg[mi][ni][r];
        float u = accu[mi][ni][r];
        float h = (g / (1.f + __expf(-g))) * u * wl[row];
        H[(size_t)(pofs + mb * 128 + row) * HID + n0 + col] = f2b(h);
      }
}

// ---------------- dense down (shared expert, initializes out) ----------------
__global__ __launch_bounds__(256, 2) void down_dense_kernel(
    const unsigned short* __restrict__ Hm,
    const unsigned short* __restrict__ WdT,
    float* __restrict__ out)
{
  __shared__ __align__(16) unsigned short As[128 * 64];
  __shared__ __align__(16) unsigned short Bs[128 * 64];
  const int m0 = blockIdx.y * 128;
  const int n0 = blockIdx.x * 128;
  const int tid = threadIdx.x;
  const int lane = tid & 63;
  const int w4 = tid >> 6;
  const int wm = (w4 & 1) * 64;
  const int wn = (w4 >> 1) * 64;
  const int c = lane & 15;
  const int q = lane >> 4;
  const int cx = c & 7;

  const int r8 = lane >> 3;
  const int swz = ((lane & 7) ^ r8) * 8;
  const int wrow = w4 * 8 + r8;

  const unsigned short* aptr[4];
  const unsigned short* bptr[4];
#pragma unroll
  for (int i = 0; i < 4; ++i) {
    aptr[i] = Hm + (size_t)(m0 + i * 32 + wrow) * HID + swz;
    bptr[i] = WdT + (size_t)(n0 + i * 32 + wrow) * HID + swz;
  }

  f32x4 acc[4][4];
#pragma unroll
  for (int mi = 0; mi < 4; ++mi)
#pragma unroll
    for (int ni = 0; ni < 4; ++ni) acc[mi][ni] = {0.f, 0.f, 0.f, 0.f};

  for (int k0 = 0; k0 < HID; k0 += 64) {
    __syncthreads();
#pragma unroll
    for (int i = 0; i < 4; ++i) {
      gload16(aptr[i] + k0, &As[i * 2048 + tid * 8]);
      gload16(bptr[i] + k0, &Bs[i * 2048 + tid * 8]);
    }
    __syncthreads();
#pragma unroll
    for (int h = 0; h < 2; ++h) {
      const int go = ((h * 4 + q) ^ cx) * 8;
      bf16x8 a[4], b[4];
#pragma unroll
      for (int mi = 0; mi < 4; ++mi)
        a[mi] = *(const bf16x8*)&As[(wm + mi * 16 + c) * 64 + go];
#pragma unroll
      for (int ni = 0; ni < 4; ++ni)
        b[ni] = *(const bf16x8*)&Bs[(wn + ni * 16 + c) * 64 + go];
#pragma unroll
      for (int mi = 0; mi < 4; ++mi)
#pragma unroll
        for (int ni = 0; ni < 4; ++ni)
          acc[mi][ni] = __builtin_amdgcn_mfma_f32_16x16x32_bf16(a[mi], b[ni], acc[mi][ni], 0, 0, 0);
    }
  }
#pragma unroll
  for (int mi = 0; mi < 4; ++mi)
#pragma unroll
    for (int r = 0; r < 4; ++r) {
      int trow = m0 + wm + mi * 16 + q * 4 + r;
#pragma unroll
      for (int ni = 0; ni < 4; ++ni) {
        int col = n0 + wn + ni * 16 + c;
        out[(size_t)trow * DIM + col] = acc[mi][ni][r];
      }
    }
}

// ---------------- merged sparse down: all experts, split-K=2, atomic scatter ----------------
__global__ __launch_bounds__(256, 2) void down_sparse_all_kernel(
    const unsigned short* __restrict__ Hm,
    const unsigned short* __restrict__ WdR,    // routed expert 0 base (slot 1 of WdA)
    const int* __restrict__ tok, const int* __restrict__ meta,
    float* __restrict__ out)
{
  const int yb = blockIdx.y;
  if (yb >= meta[15]) return;
  const int bm = meta[16 + yb];
  const int e = bm & 7, mb = bm >> 3;
  const int cnt = meta[e];
  const int pofs = meta[8 + e];
  const unsigned short* WdT = WdR + (size_t)e * ((size_t)HID * DIM);
  const int kbase = blockIdx.z * (HID / 2);

  __shared__ __align__(16) unsigned short As[128 * 64];
  __shared__ __align__(16) unsigned short Bs[128 * 64];
  __shared__ int tl[128];
  const int n0 = blockIdx.x * 128;
  const int tid = threadIdx.x;
  const int lane = tid & 63;
  const int w4 = tid >> 6;
  const int wm = (w4 & 1) * 64;
  const int wn = (w4 >> 1) * 64;
  const int c = lane & 15;
  const int q = lane >> 4;
  const int cx = c & 7;

  if (tid < 128)
    tl[tid] = (mb * 128 + tid < cnt) ? tok[pofs + mb * 128 + tid] : 0;

  const int r8 = lane >> 3;
  const int swz = ((lane & 7) ^ r8) * 8;
  const int wrow = w4 * 8 + r8;

  const unsigned short* aptr[4];
  const unsigned short* bptr[4];
#pragma unroll
  for (int i = 0; i < 4; ++i) {
    aptr[i] = Hm + (size_t)(pofs + mb * 128 + i * 32 + wrow) * HID + kbase + swz;
    bptr[i] = WdT + (size_t)(n0 + i * 32 + wrow) * HID + kbase + swz;
  }

  f32x4 acc[4][4];
#pragma unroll
  for (int mi = 0; mi < 4; ++mi)
#pragma unroll
    for (int ni = 0; ni < 4; ++ni) acc[mi][ni] = {0.f, 0.f, 0.f, 0.f};

  for (int k0 = 0; k0 < HID / 2; k0 += 64) {
    __syncthreads();
#pragma unroll
    for (int i = 0; i < 4; ++i) {
      gload16(aptr[i] + k0, &As[i * 2048 + tid * 8]);
      gload16(bptr[i] + k0, &Bs[i * 2048 + tid * 8]);
    }
    __syncthreads();
#pragma unroll
    for (int h = 0; h < 2; ++h) {
      const int go = ((h * 4 + q) ^ cx) * 8;
      bf16x8 a[4], b[4];
#pragma unroll
      for (int mi = 0; mi < 4; ++mi)
        a[mi] = *(const bf16x8*)&As[(wm + mi * 16 + c) * 64 + go];
#pragma unroll
      for (int ni = 0; ni < 4; ++ni)
        b[ni] = *(const bf16x8*)&Bs[(wn + ni * 16 + c) * 64 + go];
#pragma unroll
      for (int mi = 0; mi < 4; ++mi)
#pragma unroll
        for (int ni = 0; ni < 4; ++ni)
          acc[mi][ni] = __builtin_amdgcn_mfma_f32_16x16x32_bf16(a[mi], b[ni], acc[mi][ni], 0, 0, 0);
    }
  }
#pragma unroll
  for (int mi = 0; mi < 4; ++mi)
#pragma unroll
    for (int r = 0; r < 4; ++r) {
      int lr = wm + mi * 16 + q * 4 + r;
      if (mb * 128 + lr < cnt) {
        int t = tl[lr];
#pragma unroll
        for (int ni = 0; ni < 4; ++ni) {
          int col = n0 + wn + ni * 16 + c;
          atomicAdd(&out[(size_t)t * DIM + col], acc[mi][ni][r]);
        }
      }
    }
}

// ---------------- fallback per-expert sparse kernels (R1 versions) ----------------
__global__ __launch_bounds__(256, 2) void gateup_sparse_kernel(
    const unsigned short* __restrict__ Xb,
    const unsigned short* __restrict__ Wgu,
    const int* __restrict__ tok, const float* __restrict__ wgt,
    const int* __restrict__ cntofs, int e,
    unsigned short* __restrict__ H)
{
  const int cnt = cntofs[e];
  const int mb = blockIdx.y;
  if (mb * 128 >= cnt) return;
  const int ofs = cntofs[8 + e];

  __shared__ __align__(16) unsigned short As[128 * 64];
  __shared__ __align__(16) unsigned short Bgs[64 * 64];
  __shared__ __align__(16) unsigned short Bus[64 * 64];
  __shared__ float wl[128];

  const int n0 = blockIdx.x * 64;
  const int tid = threadIdx.x;
  const int lane = tid & 63;
  const int w = tid >> 6;
  const int wm = (w & 1) * 64;
  const int wn = (w >> 1) * 32;
  const int c = lane & 15;
  const int q = lane >> 4;
  const int cx = c & 7;

  if (tid < 128)
    wl[tid] = (mb * 128 + tid < cnt) ? wgt[ofs + mb * 128 + tid] : 0.f;

  const unsigned short* Wg = Wgu;
  const unsigned short* Wu = Wgu + (size_t)HID * DIM;

  const int r8 = lane >> 3;
  const int swz = ((lane & 7) ^ r8) * 8;
  const int wrow = w * 8 + r8;

  const unsigned short* aptr[4];
#pragma unroll
  for (int i = 0; i < 4; ++i) {
    int s = mb * 128 + i * 32 + wrow;
    int t = (s < cnt) ? tok[ofs + s] : 0;
    aptr[i] = Xb + (size_t)t * DIM + swz;
  }
  const unsigned short* gptr[2];
  const unsigned short* uptr[2];
#pragma unroll
  for (int i = 0; i < 2; ++i) {
    gptr[i] = Wg + (size_t)(n0 + i * 32 + wrow) * DIM + swz;
    uptr[i] = Wu + (size_t)(n0 + i * 32 + wrow) * DIM + swz;
  }

  f32x4 accg[4][2], accu[4][2];
#pragma unroll
  for (int mi = 0; mi < 4; ++mi)
#pragma unroll
    for (int ni = 0; ni < 2; ++ni) {
      accg[mi][ni] = {0.f, 0.f, 0.f, 0.f};
      accu[mi][ni] = {0.f, 0.f, 0.f, 0.f};
    }

  for (int k0 = 0; k0 < DIM; k0 += 64) {
    __syncthreads();
#pragma unroll
    for (int i = 0; i < 4; ++i) gload16(aptr[i] + k0, &As[i * 2048 + tid * 8]);
#pragma unroll
    for (int i = 0; i < 2; ++i) {
      gload16(gptr[i] + k0, &Bgs[i * 2048 + tid * 8]);
      gload16(uptr[i] + k0, &Bus[i * 2048 + tid * 8]);
    }
    __syncthreads();
#pragma unroll
    for (int h = 0; h < 2; ++h) {
      const int go = ((h * 4 + q) ^ cx) * 8;
      bf16x8 a[4], bg[2], bu[2];
#pragma unroll
      for (int mi = 0; mi < 4; ++mi)
        a[mi] = *(const bf16x8*)&As[(wm + mi * 16 + c) * 64 + go];
#pragma unroll
      for (int ni = 0; ni < 2; ++ni) {
        bg[ni] = *(const bf16x8*)&Bgs[(wn + ni * 16 + c) * 64 + go];
        bu[ni] = *(const bf16x8*)&Bus[(wn + ni * 16 + c) * 64 + go];
      }
#pragma unroll
      for (int mi = 0; mi < 4; ++mi)
#pragma unroll
        for (int ni = 0; ni < 2; ++ni) {
          accg[mi][ni] = __builtin_amdgcn_mfma_f32_16x16x32_bf16(a[mi], bg[ni], accg[mi][ni], 0, 0, 0);
          accu[mi][ni] = __builtin_amdgcn_mfma_f32_16x16x32_bf16(a[mi], bu[ni], accu[mi][ni], 0, 0, 0);
        }
    }
  }
#pragma unroll
  for (int mi = 0; mi < 4; ++mi)
#pragma unroll
    for (int ni = 0; ni < 2; ++ni)
#pragma unroll
      for (int r = 0; r < 4; ++r) {
        int row = wm + mi * 16 + q * 4 + r;
        int col = wn + ni * 16 + c;
        float g = accg[mi][ni][r];
        float u = accu[mi][ni][r];
        float h = (g / (1.f + __expf(-g))) * u * wl[row];
        H[(size_t)(mb * 128 + row) * HID + n0 + col] = f2b(h);
      }
}

__global__ __launch_bounds__(256, 2) void down_sparse_kernel(
    const unsigned short* __restrict__ Hm,
    const unsigned short* __restrict__ WdT,
    const int* __restrict__ tok, const int* __restrict__ cntofs, int e,
    float* __restrict__ out)
{
  const int cnt = cntofs[e];
  const int mb = blockIdx.y;
  if (mb * 128 >= cnt) return;
  const int ofs = cntofs[8 + e];
  const int kbase = blockIdx.z * (HID / 2);

  __shared__ __align__(16) unsigned short As[128 * 64];
  __shared__ __align__(16) unsigned short Bs[128 * 64];
  __shared__ int tl[128];
  const int n0 = blockIdx.x * 128;
  const int tid = threadIdx.x;
  const int lane = tid & 63;
  const int w4 = tid >> 6;
  const int wm = (w4 & 1) * 64;
  const int wn = (w4 >> 1) * 64;
  const int c = lane & 15;
  const int q = lane >> 4;
  const int cx = c & 7;

  if (tid < 128)
    tl[tid] = (mb * 128 + tid < cnt) ? tok[ofs + mb * 128 + tid] : 0;

  const int r8 = lane >> 3;
  const int swz = ((lane & 7) ^ r8) * 8;
  const int wrow = w4 * 8 + r8;

  const unsigned short* aptr[4];
  const unsigned short* bptr[4];
#pragma unroll
  for (int i = 0; i < 4; ++i) {
    aptr[i] = Hm + (size_t)(mb * 128 + i * 32 + wrow) * HID + kbase + swz;
    bptr[i] = WdT + (size_t)(n0 + i * 32 + wrow) * HID + kbase + swz;
  }

  f32x4 acc[4][4];
#pragma unroll
  for (int mi = 0; mi < 4; ++mi)
#pragma unroll
    for (int ni = 0; ni < 4; ++ni) acc[mi][ni] = {0.f, 0.f, 0.f, 0.f};

  for (int k0 = 0; k0 < HID / 2; k0 += 64) {
    __syncthreads();
#pragma unroll
    for (int i = 0; i < 4; ++i) {
      gload16(aptr[i] + k0, &As[i * 2048 + tid * 8]);
      gload16(bptr[i] + k0, &Bs[i * 2048 + tid * 8]);
    }
    __syncthreads();
#pragma unroll
    for (int h = 0; h < 2; ++h) {
      const int go = ((h * 4 + q) ^ cx) * 8;
      bf16x8 a[4], b[4];
#pragma unroll
      for (int mi = 0; mi < 4; ++mi)
        a[mi] = *(const bf16x8*)&As[(wm + mi * 16 + c) * 64 + go];
#pragma unroll
      for (int ni = 0; ni < 4; ++ni)
        b[ni] = *(const bf16x8*)&Bs[(wn + ni * 16 + c) * 64 + go];
#pragma unroll
      for (int mi = 0; mi < 4; ++mi)
#pragma unroll
        for (int ni = 0; ni < 4; ++ni)
          acc[mi][ni] = __builtin_amdgcn_mfma_f32_16x16x32_bf16(a[mi], b[ni], acc[mi][ni], 0, 0, 0);
    }
  }
#pragma unroll
  for (int mi = 0; mi < 4; ++mi)
#pragma unroll
    for (int r = 0; r < 4; ++r) {
      int lr = wm + mi * 16 + q * 4 + r;
      if (mb * 128 + lr < cnt) {
        int t = tl[lr];
#pragma unroll
        for (int ni = 0; ni < 4; ++ni) {
          int col = n0 + wn + ni * 16 + c;
          atomicAdd(&out[(size_t)t * DIM + col], acc[mi][ni][r]);
        }
      }
    }
}

extern "C" void kernel_launch(void* const* d_in, const int* in_sizes, int n_in,
                              void* d_out, int out_size, void* d_ws, size_t ws_size,
                              hipStream_t stream) {
  (void)in_sizes; (void)n_in; (void)out_size;
  const float* x   = (const float*)d_in[0];
  const float* sg  = (const float*)d_in[1];
  const float* su  = (const float*)d_in[2];
  const float* sd  = (const float*)d_in[3];
  const float* rg  = (const float*)d_in[4];
  const float* ru  = (const float*)d_in[5];
  const float* rd  = (const float*)d_in[6];
  const float* wrr = (const float*)d_in[7];
  const float* rb  = (const float*)d_in[8];
  float* out = (float*)d_out;

  char* ws = (char*)d_ws;
  dim3 blk(256);

  if (ws_size >= MW_NEED) {
    // -------- merged schedule: 8 launches total --------
    unsigned short* Xb   = (unsigned short*)(ws + MW_XB);
    unsigned short* H    = (unsigned short*)(ws + MW_H);
    unsigned short* WguA = (unsigned short*)(ws + MW_WGU);
    unsigned short* WdA  = (unsigned short*)(ws + MW_WD);
    int*   tok           = (int*)(ws + MW_TOK);
    float* wgt           = (float*)(ws + MW_WGT);
    int*   meta          = (int*)(ws + MW_META);
    int*   eidx = (int*)H;                       // parked in H, consumed by build
    float* ew   = (float*)((char*)H + 32768);

    router_kernel<<<dim3(TOKENS / 256), blk, 0, stream>>>(x, wrr, rb, eidx, ew);
    xcvt_kernel<<<dim3(TOKENS * DIM / (8 * 256)), blk, 0, stream>>>(x, Xb);
    build_kernel<<<dim3(1), blk, 0, stream>>>(eidx, ew, tok, wgt, meta, 1);
    transpose_all_kernel<<<dim3(8 * 2112), blk, 0, stream>>>(sg, su, sd, rg, ru, rd, WguA, WdA);

    gateup_kernel<<<dim3(HID / 64, TOKENS / 128), blk, 0, stream>>>(Xb, WguA, H);
    down_dense_kernel<<<dim3(DIM / 128, TOKENS / 128), blk, 0, stream>>>(H, WdA, out);

    const unsigned short* WguRt = WguA + 2 * (size_t)HID * DIM;   // routed slot base
    const unsigned short* WdRt  = WdA + (size_t)HID * DIM;
    gateup_sparse_all_kernel<<<dim3(HID / 64, 135), blk, 0, stream>>>(Xb, WguRt, tok, wgt, meta, H);
    down_sparse_all_kernel<<<dim3(DIM / 128, 135, 2), blk, 0, stream>>>(H, WdRt, tok, meta, out);
  } else {
    // -------- fallback: R1 per-expert schedule --------
    unsigned short* Xb  = (unsigned short*)ws;
    unsigned short* H   = (unsigned short*)(ws + 16777216);
    unsigned short* Wgu = (unsigned short*)(ws + 62914560);
    unsigned short* Wd  = (unsigned short*)(ws + 74448896);
    int*   tok          = (int*)(ws + 80216064);
    float* wgt          = (float*)(ws + 80281600);
    int*   meta         = (int*)(ws + 80347136);
    int*   eidx = (int*)H;
    float* ew   = (float*)((char*)H + 32768);

    router_kernel<<<dim3(TOKENS / 256), blk, 0, stream>>>(x, wrr, rb, eidx, ew);
    xcvt_kernel<<<dim3(TOKENS * DIM / (8 * 256)), blk, 0, stream>>>(x, Xb);
    build_kernel<<<dim3(1), blk, 0, stream>>>(eidx, ew, tok, wgt, meta, 0);

    dim3 ggu(HID / 64, TOKENS / 128);
    dim3 gdn(DIM / 128, TOKENS / 128);
    dim3 gdns(DIM / 128, TOKENS / 128, 2);

    for (int e = 0; e < 8; ++e) {
      const float* eg = (e == 0) ? sg : rg + (size_t)(e - 1) * DIM * HID;
      const float* eu = (e == 0) ? su : ru + (size_t)(e - 1) * DIM * HID;
      const float* ed = (e == 0) ? sd : rd + (size_t)(e - 1) * HID * DIM;
      transpose_all_kernel<<<dim3(2112), blk, 0, stream>>>(eg, eu, ed, eg, eu, ed, Wgu, Wd);
      if (e == 0) {
        gateup_kernel<<<ggu, blk, 0, stream>>>(Xb, Wgu, H);
        down_dense_kernel<<<gdn, blk, 0, stream>>>(H, Wd, out);
      } else {
        gateup_sparse_kernel<<<ggu, blk, 0, stream>>>(Xb, Wgu, tok, wgt, meta, e - 1, H);
        down_sparse_kernel<<<gdns, blk, 0, stream>>>(H, Wd, tok, meta, e - 1, out);
      }
    }
  }
}